// Round 13
// baseline (1521.691 us; speedup 1.0000x reference)
//
#include <hip/hip_runtime.h>
#include <hip/hip_bf16.h>
#include <stdint.h>

#define HD 4096
#define VD 32000
#define BT 2048        // B*T rows
#define TT 512
#define IGNORE_IDX (-100)

// bf16 8-wave main GEMM geometry: 256x128 block, BKT=32, wave-tile 64x64
#define BM 256
#define BN 128
#define BKT 32
#define KT (HD / BKT)          // 128 K-tiles
#define NB (VD / BN)           // 250
#define MB (BT / BM)           // 8
#define NWG2 (MB * NB * 2)     // 4000

// partials granularity: 64 columns per chunk (wave-owned) — shared with fallback
#define NCHUNK (VD / 64)       // 500

typedef __attribute__((ext_vector_type(8))) short short8;
typedef __attribute__((ext_vector_type(4))) float f32x4;

__device__ __forceinline__ uint16_t f2bf(float f) {
    uint32_t u = __float_as_uint(f);
    u += 0x7FFFu + ((u >> 16) & 1u);   // round-to-nearest-even
    return (uint16_t)(u >> 16);
}

__device__ __forceinline__ void gload16(const void* g, void* l) {
    __builtin_amdgcn_global_load_lds(
        (const __attribute__((address_space(1))) void*)g,
        (__attribute__((address_space(3))) void*)l, 16, 0, 0);
}

// ---------------- kernel 0a: convert x inputs f32 -> bf16 ----------------
__global__ void convert_x(const float* __restrict__ x0, const float* __restrict__ x1,
                          uint16_t* __restrict__ xbf) {
    const int64_t n4 = (int64_t)BT * HD / 4;
    ushort4* o0 = (ushort4*)xbf;
    ushort4* o1 = (ushort4*)(xbf + (int64_t)BT * HD);
    for (int64_t i = blockIdx.x * (int64_t)blockDim.x + threadIdx.x; i < n4;
         i += (int64_t)gridDim.x * blockDim.x) {
        float4 a = ((const float4*)x0)[i];
        float4 b = ((const float4*)x1)[i];
        ushort4 ua, ub;
        ua.x = f2bf(a.x); ua.y = f2bf(a.y); ua.z = f2bf(a.z); ua.w = f2bf(a.w);
        ub.x = f2bf(b.x); ub.y = f2bf(b.y); ub.z = f2bf(b.z); ub.w = f2bf(b.w);
        o0[i] = ua;
        o1[i] = ub;
    }
}

// ---------------- kernel 0b: convert weights f32 -> bf16 ----------------
__global__ void convert_w(const float* __restrict__ w0, const float* __restrict__ w1,
                          uint16_t* __restrict__ wbf) {
    const int64_t n4 = (int64_t)VD * HD / 4;
    ushort4* o0 = (ushort4*)wbf;
    ushort4* o1 = (ushort4*)(wbf + (int64_t)VD * HD);
    for (int64_t i = blockIdx.x * (int64_t)blockDim.x + threadIdx.x; i < n4;
         i += (int64_t)gridDim.x * blockDim.x) {
        float4 a = ((const float4*)w0)[i];
        float4 b = ((const float4*)w1)[i];
        ushort4 ua, ub;
        ua.x = f2bf(a.x); ua.y = f2bf(a.y); ua.z = f2bf(a.z); ua.w = f2bf(a.w);
        ub.x = f2bf(b.x); ub.y = f2bf(b.y); ub.z = f2bf(b.z); ub.w = f2bf(b.w);
        o0[i] = ua;
        o1[i] = ub;
    }
}

// ---------------- kernel 1 (main): 256x128 GEMM + LSE partials, 2 blocks/CU ----------------
// 3-buffer LDS pipeline, 2-tiles-ahead prefetch, counted vmcnt(3) (never 0 mid-loop).
__global__ __launch_bounds__(512, 4) void gemm_lse_bf(
    const uint16_t* __restrict__ xbf, const uint16_t* __restrict__ wbf,
    const float* __restrict__ b0, const float* __restrict__ b1,
    const int* __restrict__ target,
    float* __restrict__ partials, float* __restrict__ tgtlog)
{
    __shared__ uint16_t As[3 * BM * BKT];  // 48 KB (3 buffers of 16 KB)
    __shared__ uint16_t Bs[3 * BN * BKT];  // 24 KB (3 buffers of 8 KB)

    const int orig = blockIdx.x;
    const int wgid = (orig & 7) * (NWG2 / 8) + (orig >> 3);
    const int mb    = wgid & 7;
    const int rest  = wgid >> 3;           // 0..499
    const int nb    = rest % NB;
    const int model = rest / NB;

    const uint16_t* xb = xbf + (size_t)model * BT * HD;
    const uint16_t* wb = wbf + (size_t)model * VD * HD;
    const float* bias  = model ? b1 : b0;

    const int row0 = mb * BM;
    const int c0   = nb * BN;

    const int tid    = threadIdx.x;
    const int lane   = tid & 63;
    const int wid    = tid >> 6;       // 0..7
    const int wr     = wid >> 1;       // 0..3  (M quarter: 64 rows)
    const int wc     = wid & 1;        // 0..1  (N half: 64 cols)

    const int lane15 = lane & 15;
    const int kg     = lane >> 4;      // 0..3 (k-slot of 8 elems)

    // staging: 64B rows, 1KB chunk = 16 rows; lane l -> row l>>2, stored slot l&3,
    // global source slot = (l&3) ^ ((l>>3)&3)   [key = ((row%16)>>1)&3]
    const int srow  = lane >> 2;               // 0..15
    const int gslot = (lane & 3) ^ ((lane >> 3) & 3);
    const uint16_t* agp = xb + (size_t)(row0 + wid * 32 + srow) * HD + gslot * 8;
    const uint16_t* bgp = wb + (size_t)(c0 + wid * 16 + srow) * HD + gslot * 8;
    char* aLdst = (char*)As + wid * 2048;      // 2 chunks per wave (+1024); +buf*16384
    char* bLdst = (char*)Bs + wid * 1024;      // 1 chunk per wave; +buf*8192

    // fragment read bases: row*64 + ((kg ^ ((lane15>>1)&3))<<4); per-mi/ni +1024 (16 rows)
    const int rswz = ((kg ^ ((lane15 >> 1) & 3)) << 4);
    const char* pA = (const char*)As + (wr * 64 + lane15) * 64 + rswz;
    const char* pB = (const char*)Bs + (wc * 64 + lane15) * 64 + rswz;

    f32x4 acc[4][4];
#pragma unroll
    for (int i = 0; i < 4; ++i)
#pragma unroll
        for (int j = 0; j < 4; ++j) acc[i][j] = (f32x4){0.f, 0.f, 0.f, 0.f};

    // prologue: stage tiles 0 and 1 into bufs 0,1; wait for tile 0 (vmcnt(3)); barrier
    gload16(bgp, bLdst);
    gload16(agp, aLdst);
    gload16(agp + (size_t)16 * HD, aLdst + 1024);
    gload16(bgp + BKT, bLdst + 8192);
    gload16(agp + BKT, aLdst + 16384);
    gload16(agp + (size_t)16 * HD + BKT, aLdst + 16384 + 1024);
    asm volatile("s_waitcnt vmcnt(3)" ::: "memory");
    __builtin_amdgcn_s_barrier();

    for (int t = 0; t < KT; ++t) {
        const int cur = t % 3;
        const int nx2 = (t + 2) % 3;
        const int CA  = cur * 16384;
        const int CBf = cur * 8192;

        // issue loads for tile t+2 (its buffer was freed at end of tile t-1)
        if (t + 2 < KT) {
            const int ko = (t + 2) * BKT;
            gload16(bgp + ko, (char*)Bs + nx2 * 8192 + wid * 1024);
            gload16(agp + ko, (char*)As + nx2 * 16384 + wid * 2048);
            gload16(agp + (size_t)16 * HD + ko, (char*)As + nx2 * 16384 + wid * 2048 + 1024);
        }

        // compute on buf cur (compiler-scheduled)
        short8 bf[4], af[4];
#pragma unroll
        for (int ni = 0; ni < 4; ++ni)
            bf[ni] = *(const short8*)(pB + ni * 1024 + CBf);
#pragma unroll
        for (int mi = 0; mi < 4; ++mi)
            af[mi] = *(const short8*)(pA + mi * 1024 + CA);
#pragma unroll
        for (int mi = 0; mi < 4; ++mi)
#pragma unroll
            for (int ni = 0; ni < 4; ++ni)
                acc[mi][ni] = __builtin_amdgcn_mfma_f32_16x16x32_bf16(
                    af[mi], bf[ni], acc[mi][ni], 0, 0, 0);

        // join: retire tile t+1's loads (issued 2 tiles ago); keep t+2's in flight
        if (t + 2 < KT)      { asm volatile("s_waitcnt vmcnt(3)" ::: "memory"); }
        else if (t + 1 < KT) { asm volatile("s_waitcnt vmcnt(0)" ::: "memory"); }
        __builtin_amdgcn_s_barrier();
    }

    // ---- epilogue: bias, per-row max/sumexp over this wave's 64 cols ----
    float bv4[4];
#pragma unroll
    for (int ni = 0; ni < 4; ++ni) bv4[ni] = bias[c0 + wc * 64 + ni * 16 + lane15];

#pragma unroll
    for (int mi = 0; mi < 4; ++mi) {
        const int grow_base = row0 + wr * 64 + mi * 16 + kg * 4;
#pragma unroll
        for (int j = 0; j < 4; ++j) {
            const int grow = grow_base + j;
            float v[4];
#pragma unroll
            for (int ni = 0; ni < 4; ++ni) v[ni] = acc[mi][ni][j] + bv4[ni];
            float m = fmaxf(fmaxf(v[0], v[1]), fmaxf(v[2], v[3]));
#pragma unroll
            for (int msk = 1; msk < 16; msk <<= 1)
                m = fmaxf(m, __shfl_xor(m, msk));
            float s = __expf(v[0] - m) + __expf(v[1] - m) +
                      __expf(v[2] - m) + __expf(v[3] - m);
#pragma unroll
            for (int msk = 1; msk < 16; msk <<= 1)
                s += __shfl_xor(s, msk);
            const int tg = target[grow];
#pragma unroll
            for (int ni = 0; ni < 4; ++ni) {
                const int gcol = c0 + wc * 64 + ni * 16 + lane15;
                if (tg == gcol) tgtlog[model * BT + grow] = v[ni];
            }
            if (lane15 == 0) {
                const size_t po = ((size_t)(model * BT + grow) * NCHUNK + nb * 2 + wc) * 2;
                partials[po]     = m;
                partials[po + 1] = s;
            }
        }
    }
}

// ---------------- kernel 1 (fallback, f32 weights): R1 structure ----------------
__global__ __launch_bounds__(256) void gemm_lse_f32(
    const uint16_t* __restrict__ xbf,
    const float* __restrict__ w0, const float* __restrict__ b0,
    const float* __restrict__ w1, const float* __restrict__ b1,
    const int* __restrict__ target,
    float* __restrict__ partials, float* __restrict__ tgtlog)
{
    const int orig = blockIdx.x;               // grid 8000
    const int wgid = (orig & 7) * 1000 + (orig >> 3);
    const int mb    = wgid & 7;
    const int rest  = wgid >> 3;
    const int chunk = rest % 500;
    const int model = rest / 500;

    const float* w    = model ? w1 : w0;
    const float* bias = model ? b1 : b0;
    const uint16_t* xb = xbf + (size_t)model * BT * HD;

    const int row0 = mb * 256;
    const int c0   = chunk * 64;

    const int tid  = threadIdx.x;
    const int lane = tid & 63;
    const int wid  = tid >> 6;

    __shared__ uint16_t As_[256 * 64];
    __shared__ uint16_t Bs_[64 * 64];

    f32x4 acc[4][4];
#pragma unroll
    for (int i = 0; i < 4; ++i)
#pragma unroll
        for (int j = 0; j < 4; ++j) acc[i][j] = (f32x4){0.f, 0.f, 0.f, 0.f};

    const int srow8 = lane >> 3;
    const int slot  = (lane & 7) ^ srow8;
    const uint16_t* agsrc = xb + (size_t)(row0 + wid * 64 + srow8) * HD + slot * 8;
    char* aldst = (char*)As_ + wid * 8192;

    const int ss   = tid & 7;
    const int srow = tid >> 3;
    const int swz_w = (srow & 7) << 4;
    const float* bptr = w + (size_t)(c0 + srow) * HD + ss * 8;

    const int lane15 = lane & 15;
    const int kg     = lane >> 4;
    const int swz_r  = (lane & 7) << 4;

    for (int kt = 0; kt < 64; ++kt) {
        const int kofs = kt * 64;
#pragma unroll
        for (int c = 0; c < 8; ++c)
            gload16(agsrc + (size_t)c * 8 * HD + kofs, aldst + c * 1024);
        {
            float4 bv[2][2];
#pragma unroll
            for (int r = 0; r < 2; ++r) {
                const float* p = bptr + (size_t)r * 32 * HD + kofs;
                bv[r][0] = *(const float4*)(p);
                bv[r][1] = *(const float4*)(p + 4);
            }
#pragma unroll
            for (int r = 0; r < 2; ++r) {
                const int row_l = srow + r * 32;
                float fv[8] = {bv[r][0].x, bv[r][0].y, bv[r][0].z, bv[r][0].w,
                               bv[r][1].x, bv[r][1].y, bv[r][1].z, bv[r][1].w};
                uint32_t pk[4];
#pragma unroll
                for (int e = 0; e < 4; ++e)
                    pk[e] = (uint32_t)f2bf(fv[2 * e]) | ((uint32_t)f2bf(fv[2 * e + 1]) << 16);
                const int off = (row_l * 128 + ss * 16) ^ swz_w;
                *(uint4*)((char*)Bs_ + off) = *(uint4*)pk;
            }
        }
        __syncthreads();
#pragma unroll
        for (int ks = 0; ks < 2; ++ks) {
            short8 af[4], bf[4];
#pragma unroll
            for (int mi = 0; mi < 4; ++mi) {
                const int arow = wid * 64 + mi * 16 + lane15;
                const int off = (arow * 128 + ks * 64 + kg * 16) ^ swz_r;
                af[mi] = *(const short8*)((const char*)As_ + off);
            }
#pragma unroll
            for (int ni = 0; ni < 4; ++ni) {
                const int brow = ni * 16 + lane15;
                const int off = (brow * 128 + ks * 64 + kg * 16) ^ swz_r;
                bf[ni] = *(const short8*)((const char*)Bs_ + off);
            }
#pragma unroll
            for (int mi = 0; mi < 4; ++mi)
#pragma unroll
                for (int ni = 0; ni < 4; ++ni)
                    acc[mi][ni] = __builtin_amdgcn_mfma_f32_16x16x32_bf16(
                        af[mi], bf[ni], acc[mi][ni], 0, 0, 0);
        }
        __syncthreads();
    }

    float bv4[4];
#pragma unroll
    for (int ni = 0; ni < 4; ++ni) bv4[ni] = bias[c0 + ni * 16 + lane15];

#pragma unroll
    for (int mi = 0; mi < 4; ++mi) {
        const int grow_base = row0 + wid * 64 + mi * 16 + kg * 4;
#pragma unroll
        for (int j = 0; j < 4; ++j) {
            const int grow = grow_base + j;
            float v[4];
#pragma unroll
            for (int ni = 0; ni < 4; ++ni) v[ni] = acc[mi][ni][j] + bv4[ni];
            float m = fmaxf(fmaxf(v[0], v[1]), fmaxf(v[2], v[3]));
#pragma unroll
            for (int msk = 1; msk < 16; msk <<= 1)
                m = fmaxf(m, __shfl_xor(m, msk));
            float s = __expf(v[0] - m) + __expf(v[1] - m) +
                      __expf(v[2] - m) + __expf(v[3] - m);
#pragma unroll
            for (int msk = 1; msk < 16; msk <<= 1)
                s += __shfl_xor(s, msk);
            const int tg = target[grow];
#pragma unroll
            for (int ni = 0; ni < 4; ++ni) {
                const int gcol = c0 + ni * 16 + lane15;
                if (tg == gcol) tgtlog[model * BT + grow] = v[ni];
            }
            if (lane15 == 0) {
                const size_t po = ((size_t)(model * BT + grow) * NCHUNK + chunk) * 2;
                partials[po]     = m;
                partials[po + 1] = s;
            }
        }
    }
}

// ---------------- kernel 2: combine chunk partials -> lse -> per-token logp ----------------
__global__ void lse_reduce(const float* __restrict__ partials,
                           const float* __restrict__ tgtlog,
                           float* __restrict__ logp) {
    const int gw = blockIdx.x * (blockDim.x >> 6) + (threadIdx.x >> 6);
    if (gw >= 2 * BT) return;
    const int lane = threadIdx.x & 63;
    const float* p = partials + (size_t)gw * NCHUNK * 2;

    float m = -1e30f;
#pragma unroll
    for (int i = 0; i < 8; ++i) {
        const int c = lane + i * 64;
        if (c < NCHUNK) m = fmaxf(m, p[c * 2]);
    }
#pragma unroll
    for (int msk = 1; msk < 64; msk <<= 1) m = fmaxf(m, __shfl_xor(m, msk));
    float s = 0.f;
#pragma unroll
    for (int i = 0; i < 8; ++i) {
        const int c = lane + i * 64;
        if (c < NCHUNK) s += p[c * 2 + 1] * __expf(p[c * 2] - m);
    }
#pragma unroll
    for (int msk = 1; msk < 64; msk <<= 1) s += __shfl_xor(s, msk);
    if (lane == 0) {
        const float lse = m + __logf(s);
        logp[gw] = tgtlog[gw] - lse;
    }
}

// ---------------- kernel 3: KTO loss ----------------
__global__ void final_loss(const float* __restrict__ logp, const int* __restrict__ target,
                           const int* __restrict__ pref, const float* __restrict__ kl,
                           float* __restrict__ out) {
    const int t = threadIdx.x;          // 512 threads
    const int lane = t & 63, wv = t >> 6;
    __shared__ float rp[4][8], rr[4][8], rm[4][8];
#pragma unroll
    for (int b = 0; b < 4; ++b) {
        const int idx = b * TT + t;
        const int tg = target[idx];
        const bool mk = (tg != IGNORE_IDX);
        float lp = mk ? logp[idx] : 0.f;
        float lr = mk ? logp[BT + idx] : 0.f;
        float mc = mk ? 1.f : 0.f;
        for (int off = 32; off; off >>= 1) {
            lp += __shfl_down(lp, off);
            lr += __shfl_down(lr, off);
            mc += __shfl_down(mc, off);
        }
        if (lane == 0) { rp[b][wv] = lp; rr[b][wv] = lr; rm[b][wv] = mc; }
    }
    __syncthreads();
    if (t == 0) {
        float loss = 0.f;
        for (int b = 0; b < 4; ++b) {
            float sp = 0.f, sr = 0.f, sm = 0.f;
            for (int i = 0; i < 8; ++i) { sp += rp[b][i]; sr += rr[b][i]; sm += rm[b][i]; }
            const float denom = fmaxf(sm, 1.f);
            const float lrb = (sp - sr) / denom;
            const float mult = pref[b] ? 1.f : -1.f;
            const float z = 0.1f * (lrb - kl[0]) * mult;
            loss += 1.f / (1.f + __expf(z));   // 1 - sigmoid(z)
        }
        out[0] = loss * 0.25f;
    }
}

extern "C" void kernel_launch(void* const* d_in, const int* in_sizes, int n_in,
                              void* d_out, int out_size, void* d_ws, size_t ws_size,
                              hipStream_t stream) {
    const float* x    = (const float*)d_in[0];
    const float* w0   = (const float*)d_in[1];
    const float* b0   = (const float*)d_in[2];
    const int*   tgt  = (const int*)d_in[3];
    const int*   pref = (const int*)d_in[4];
    const float* xr   = (const float*)d_in[5];
    const float* w1   = (const float*)d_in[6];
    const float* b1   = (const float*)d_in[7];
    const float* kl   = (const float*)d_in[8];
    float* out = (float*)d_out;

    // ws layout: xbf | partials | tgtlog | logp | [wbf if it fits]
    const size_t xbf_b  = (size_t)2 * BT * HD * 2;          // 33.55 MB
    const size_t part_b = (size_t)2 * BT * NCHUNK * 2 * 4;  // 16.38 MB
    const size_t tl_b   = (size_t)2 * BT * 4;
    const size_t wbf_b  = (size_t)2 * VD * HD * 2;          // 524.3 MB

    char* wp = (char*)d_ws;
    uint16_t* xbf     = (uint16_t*)wp;                 wp += xbf_b;
    float*    partials = (float*)wp;                   wp += part_b;
    float*    tgtlog   = (float*)wp;                   wp += tl_b;
    float*    logp     = (float*)wp;                   wp += tl_b;
    uint16_t* wbf      = (uint16_t*)wp;
    const bool use_wbf = ws_size >= (xbf_b + part_b + 2 * tl_b + wbf_b);

    hipLaunchKernelGGL(convert_x, dim3(1024), dim3(256), 0, stream, x, xr, xbf);
    if (use_wbf) {
        hipLaunchKernelGGL(convert_w, dim3(4096), dim3(256), 0, stream, w0, w1, wbf);
        hipLaunchKernelGGL(gemm_lse_bf, dim3(NWG2), dim3(512), 0, stream,
                           xbf, wbf, b0, b1, tgt, partials, tgtlog);
    } else {
        hipLaunchKernelGGL(gemm_lse_f32, dim3(8000), dim3(256), 0, stream,
                           xbf, w0, b0, w1, b1, tgt, partials, tgtlog);
    }
    hipLaunchKernelGGL(lse_reduce, dim3(2 * BT / 4), dim3(256), 0, stream,
                       partials, tgtlog, logp);
    hipLaunchKernelGGL(final_loss, dim3(1), dim3(512), 0, stream, logp, tgt, pref, kl, out);
}